// Round 8
// baseline (6267.637 us; speedup 1.0000x reference)
//
#include <hip/hip_runtime.h>
#include <math.h>

#define L 256
#define P 1024
#define P1 1025
#define TWOL 512
#define NBLK 64
#define TPB 512

typedef unsigned long long u64;

// ws offsets (float units)
#define OFF_VH   0                        // [1025][256]
#define OFF_WH   (P1*L)                   // [1024][1024]  WH[j][g] = (W_ih@H_r)[g][j] transposed
#define OFF_TE   (OFF_WH + 1024*1024)     // u64 [2][1026] tagged e
#define OFF_TH   (OFF_TE + 2*1026*2)      // u64 [2][256]  tagged h

#define SCOPE_AGENT __HIP_MEMORY_SCOPE_AGENT

__device__ __forceinline__ u64 ld64(const u64* p) {
  return __hip_atomic_load(p, __ATOMIC_RELAXED, SCOPE_AGENT);
}
__device__ __forceinline__ void st64(u64* p, u64 v) {
  __hip_atomic_store(p, v, __ATOMIC_RELAXED, SCOPE_AGENT);
}
__device__ __forceinline__ u64 pk(float v, unsigned t) {
  return ((u64)t << 32) | (u64)__float_as_uint(v);
}
__device__ __forceinline__ unsigned tg_of(u64 x) { return (unsigned)(x >> 32); }
__device__ __forceinline__ float val_of(u64 x) { return __uint_as_float((unsigned)x); }

__device__ __forceinline__ float fast_tanh(float x) {
  float u = __expf(2.0f * x);
  return 1.0f - 2.0f * __builtin_amdgcn_rcpf(1.0f + u);
}
__device__ __forceinline__ float sigm(float x) {
  return __builtin_amdgcn_rcpf(1.0f + __expf(-x));
}
__device__ __forceinline__ float wave_reduce(float v) {
  #pragma unroll
  for (int o = 32; o > 0; o >>= 1) v += __shfl_xor(v, o, 64);
  return v;
}

__global__ void init_kernel(float* __restrict__ ws) {
  const int tid = threadIdx.x;
  u64* th = (u64*)(ws + OFF_TH);
  for (int i = tid; i < 256; i += 256) st64(th + i, 0ull);  // h(0): tag 0, val 0
}

// VH[j][i] and WH[j][g]; H_r col 1024 = 0 so VH[1024]=0, WH row 1024 unused (zero contribution).
__global__ void __launch_bounds__(256) prep_gemm(const float* __restrict__ H,
                                                 const float* __restrict__ W1,
                                                 const float* __restrict__ W_ih,
                                                 float* __restrict__ ws) {
  __shared__ float As[32 * 64];
  __shared__ float Bs[64 * 33];
  const int tid = threadIdx.x;
  const int j0 = blockIdx.x * 64;
  const int n0 = blockIdx.y * 64;
  const int tx = tid & 15, ty = tid >> 4;
  float acc[4][4] = {{0.f,0.f,0.f,0.f},{0.f,0.f,0.f,0.f},{0.f,0.f,0.f,0.f},{0.f,0.f,0.f,0.f}};
  for (int ks = 0; ks < TWOL; ks += 32) {
    for (int idx = tid; idx < 2048; idx += 256) {
      int kk = idx >> 6, jj = idx & 63;
      int j = j0 + jj;
      As[kk * 64 + jj] = (j < P) ? H[(ks + kk) * P + j] : 0.0f;
    }
    for (int idx = tid; idx < 2048; idx += 256) {
      int kk = idx & 31, nn = idx >> 5;
      int n = n0 + nn;
      Bs[nn * 33 + kk] = (n < L) ? W1[n * TWOL + ks + kk] : W_ih[(n - L) * TWOL + ks + kk];
    }
    __syncthreads();
    #pragma unroll
    for (int kk = 0; kk < 32; ++kk) {
      float4 a = *(const float4*)&As[kk * 64 + ty * 4];
      #pragma unroll
      for (int r = 0; r < 4; ++r) {
        float bb = Bs[(tx * 4 + r) * 33 + kk];
        acc[r][0] += a.x * bb; acc[r][1] += a.y * bb;
        acc[r][2] += a.z * bb; acc[r][3] += a.w * bb;
      }
    }
    __syncthreads();
  }
  #pragma unroll
  for (int q = 0; q < 4; ++q) {
    int j = j0 + ty * 4 + q;
    int n = n0 + tx * 4;
    if (n < L) {
      if (j <= P) {
        float4 v = make_float4(acc[0][q], acc[1][q], acc[2][q], acc[3][q]);
        *(float4*)&ws[OFF_VH + j * L + n] = v;
      }
    } else {
      if (j < P) {
        #pragma unroll
        for (int r = 0; r < 4; ++r)
          ws[OFF_WH + j * 1024 + (n + r - L)] = acc[r][q];
      }
    }
  }
}

// 64 symmetric blocks: block b owns attention rows [16b,16b+16), h-indices [4b,4b+4),
// gate rows {q*256 + 4b + k : q<4, k<4}. Only h and e are exchanged (tagged u64).
__global__ void __launch_bounds__(TPB, 1) scan_kernel(
    const float* __restrict__ W2, const float* __restrict__ b2,
    const float* __restrict__ w3, const float* __restrict__ cin,
    const float* __restrict__ W_hh, const float* __restrict__ b_ih,
    const float* __restrict__ b_hh,
    float* __restrict__ ws, float* __restrict__ out) {
  __shared__ float e_lds[1028];
  __shared__ float h_lds[256];
  __shared__ float x2_lds[272];     // padded i + (i>>4)
  __shared__ float prt[512];        // [32 ch][16 g]
  __shared__ float hhp[512];        // [32 ch][16 g]
  __shared__ float sred[8];
  __shared__ float gate_s[16];
  __shared__ float cc_s[4];

  const int tid = threadIdx.x;
  const int b = blockIdx.x;
  const int lane = tid & 63, wid = tid >> 6;
  u64* te = (u64*)(ws + OFF_TE);
  u64* th = (u64*)(ws + OFF_TH);

  const int row = tid >> 5, sub = tid & 31;   // attention mapping: 16 rows x 32 threads
  const int g = tid & 15, ch = tid >> 4;      // gate mapping: 16 g-cols x 32 j-chunks
  const int j0 = 16 * b, i0 = 4 * b;
  const int G = (g >> 2) * L + i0 + (g & 3);  // global gate row
  const bool xr = (b == NBLK - 1) && (row == 0);

  // ---- register preloads ----
  float vh[8], w3r[8], whh[8], w2h[128], wreg[32];
  #pragma unroll
  for (int q = 0; q < 8; ++q) vh[q] = ws[OFF_VH + (j0 + row) * L + 8 * sub + q];
  #pragma unroll
  for (int q = 0; q < 8; ++q) w3r[q] = w3[8 * sub + q];
  #pragma unroll
  for (int q = 0; q < 8; ++q) whh[q] = W_hh[G * L + 8 * ch + q];
  {
    const float* wsrc = W2 + (tid >> 1) * L + (tid & 1) * 128;
    #pragma unroll
    for (int m = 0; m < 128; ++m) w2h[m] = wsrc[m];
  }
  #pragma unroll
  for (int m = 0; m < 32; ++m)
    wreg[m] = ws[OFF_WH + (32 * ch + m) * 1024 + G];
  const float b2r = ((tid & 1) == 0) ? b2[tid >> 1] : 0.0f;
  const float bz  = (tid < 16) ? (b_ih[G] + b_hh[G]) : 0.0f;
  const float cb  = cin[0];
  if (tid < 4) cc_s[tid] = 0.0f;
  __syncthreads();

  for (int t = 1; t <= P; ++t) {
    const int ppar = (t - 1) & 1, cpar = t & 1;
    const unsigned tprev = (unsigned)(t - 1), tcur = (unsigned)t;

    // phase 1: poll h(t-1) — tag rides with value, one u64 per thread (tid<256)
    if (tid < 256) {
      const u64* hp = th + ppar * 256 + tid;
      u64 hv;
      for (;;) { hv = ld64(hp); if (__all(tg_of(hv) == tprev)) break; }
      h_lds[tid] = val_of(hv);
    }
    __syncthreads();                                   // B1

    // phase 2: x2 = W2@h + b2 (half-rows in regs, pair-combine via shfl)
    {
      const float* hsrc = h_lds + (tid & 1) * 128;
      float a = 0.0f;
      #pragma unroll
      for (int u = 0; u < 32; ++u) {
        float4 h4 = *(const float4*)&hsrc[4 * u];
        a += w2h[4*u] * h4.x + w2h[4*u+1] * h4.y + w2h[4*u+2] * h4.z + w2h[4*u+3] * h4.w;
      }
      a += __shfl_xor(a, 1, 64);
      if ((tid & 1) == 0) x2_lds[(tid >> 1) + (tid >> 5)] = b2r + a;
      // hh partial for own gate rows (W_hh slice in regs) — off critical path
      float4 ha = *(const float4*)&h_lds[8 * ch];
      float4 hb = *(const float4*)&h_lds[8 * ch + 4];
      float ah = whh[0]*ha.x + whh[1]*ha.y + whh[2]*ha.z + whh[3]*ha.w
               + whh[4]*hb.x + whh[5]*hb.y + whh[6]*hb.z + whh[7]*hb.w;
      hhp[ch * 16 + g] = ah;
    }
    __syncthreads();                                   // B2

    // phase 3: tanh + e for own 16 rows, publish tagged e
    {
      const int xb = 8 * sub + (sub >> 1);
      float s = 0.0f;
      #pragma unroll
      for (int q = 0; q < 8; ++q) s += w3r[q] * fast_tanh(vh[q] + x2_lds[xb + q]);
      #pragma unroll
      for (int o = 1; o < 32; o <<= 1) s += __shfl_xor(s, o, 64);
      if (sub == 0) {
        float vf = s + cb;
        out[t * P1 + j0 + row] = vf;
        st64(te + cpar * 1026 + j0 + row, pk(__expf(vf), tcur));
      }
      if (xr) {                                        // terminal j=1024 (VH row = 0)
        float s2 = 0.0f;
        #pragma unroll
        for (int q = 0; q < 8; ++q) s2 += w3r[q] * fast_tanh(x2_lds[xb + q]);
        #pragma unroll
        for (int o = 1; o < 32; o <<= 1) s2 += __shfl_xor(s2, o, 64);
        if (sub == 0) {
          float vf2 = s2 + cb;
          out[t * P1 + 1024] = vf2;
          st64(te + cpar * 1026 + 1024, pk(__expf(vf2), tcur));
        }
      }
    }

    // phase 4: e-poll (2 tagged u64/thread; thread 511 also takes slot 1024)
    {
      const u64* ep = te + cpar * 1026;
      const int ja = 2 * tid;
      const bool three = (tid == TPB - 1);
      u64 e0, e1, e2 = 0;
      for (;;) {
        e0 = ld64(ep + ja); e1 = ld64(ep + ja + 1);
        bool ok = (tg_of(e0) == tcur) & (tg_of(e1) == tcur);
        if (three) { e2 = ld64(ep + 1024); ok &= (tg_of(e2) == tcur); }
        if (__all(ok)) break;
      }
      e_lds[ja] = val_of(e0); e_lds[ja + 1] = val_of(e1);
      float se = val_of(e0) + val_of(e1);
      if (three) { e_lds[1024] = val_of(e2); se += val_of(e2); }
      se = wave_reduce(se);
      if (lane == 0) sred[wid] = se;
    }
    __syncthreads();                                   // B3

    // phase 5: gx for own 16 gate rows — WHT slice in registers, e from LDS
    {
      float acc = 0.0f;
      #pragma unroll
      for (int u = 0; u < 8; ++u) {
        float4 e4 = *(const float4*)&e_lds[32 * ch + 4 * u];
        acc += e4.x * wreg[4*u] + e4.y * wreg[4*u+1] + e4.z * wreg[4*u+2] + e4.w * wreg[4*u+3];
      }
      prt[ch * 16 + g] = acc;
    }
    __syncthreads();                                   // B4

    // phase 6: gates + cell + publish h (wave 0; in-wave LDS ordering)
    if (tid < 16) {
      float S = sred[0] + sred[1] + sred[2] + sred[3]
              + sred[4] + sred[5] + sred[6] + sred[7];
      float gx = 0.0f, hh = 0.0f;
      #pragma unroll
      for (int q = 0; q < 32; ++q) { gx += prt[q * 16 + tid]; hh += hhp[q * 16 + tid]; }
      gate_s[tid] = gx * __builtin_amdgcn_rcpf(S) + hh + bz;
    }
    if (tid < 4) {
      float gi = gate_s[tid], gf = gate_s[4 + tid];
      float gg2 = gate_s[8 + tid], go = gate_s[12 + tid];
      float cn = sigm(gf) * cc_s[tid] + sigm(gi) * fast_tanh(gg2);
      float hn = sigm(go) * fast_tanh(cn);
      cc_s[tid] = cn;
      st64(th + cpar * 256 + i0 + tid, pk(hn, tcur));
    }
    // no trailing barrier: next-iter h-poll self-synchronizes; all LDS WARs barrier-separated
  }
}

__global__ void __launch_bounds__(256) final_kernel(float* __restrict__ out) {
  __shared__ float buf[P1];
  __shared__ float red[8];
  const int row = blockIdx.x;
  const int tid = threadIdx.x;
  const int lane = tid & 63, wid = tid >> 6;
  if (row == 0) {
    const float v = -logf((float)P1);
    for (int idx = tid; idx < P1; idx += 256) out[idx] = v;
    return;
  }
  float* o = out + row * P1;
  for (int idx = tid; idx < P1; idx += 256) buf[idx] = o[idx];
  __syncthreads();
  float p = 0.0f;
  for (int idx = tid; idx < P1; idx += 256) p += __expf(buf[idx]);
  p = wave_reduce(p);
  if (lane == 0) red[wid] = p;
  __syncthreads();
  const float s1 = red[0] + red[1] + red[2] + red[3];
  const float inv = __builtin_amdgcn_rcpf(s1);
  __syncthreads();
  float p2 = 0.0f;
  for (int idx = tid; idx < P1; idx += 256) {
    float be = __expf(buf[idx]) * inv;   // beta
    buf[idx] = be;
    p2 += __expf(be);
  }
  p2 = wave_reduce(p2);
  if (lane == 0) red[wid] = p2;
  __syncthreads();
  const float ls2 = logf(red[0] + red[1] + red[2] + red[3]);
  for (int idx = tid; idx < P1; idx += 256) o[idx] = buf[idx] - ls2;
}

extern "C" void kernel_launch(void* const* d_in, const int* in_sizes, int n_in,
                              void* d_out, int out_size, void* d_ws, size_t ws_size,
                              hipStream_t stream) {
  (void)in_sizes; (void)n_in; (void)out_size; (void)ws_size;
  const float* H    = (const float*)d_in[0];
  const float* W1   = (const float*)d_in[1];
  const float* W2   = (const float*)d_in[2];
  const float* b2   = (const float*)d_in[3];
  const float* w3   = (const float*)d_in[4];
  const float* c    = (const float*)d_in[5];
  const float* W_ih = (const float*)d_in[6];
  const float* W_hh = (const float*)d_in[7];
  const float* b_ih = (const float*)d_in[8];
  const float* b_hh = (const float*)d_in[9];
  float* out = (float*)d_out;
  float* ws  = (float*)d_ws;

  hipLaunchKernelGGL(init_kernel, dim3(1), dim3(256), 0, stream, ws);
  hipLaunchKernelGGL(prep_gemm, dim3(17, 20), dim3(256), 0, stream, H, W1, W_ih, ws);
  hipLaunchKernelGGL(scan_kernel, dim3(NBLK), dim3(TPB), 0, stream,
                     W2, b2, w3, c, W_hh, b_ih, b_hh, ws, out);
  hipLaunchKernelGGL(final_kernel, dim3(P1), dim3(256), 0, stream, out);
}